// Round 1
// baseline (300.978 us; speedup 1.0000x reference)
//
#include <hip/hip_runtime.h>
#include <math.h>

#define NPTS 8192
#define TPB  256

// ---------------------------------------------------------------------------
// Branchless sorted-descending top-4 insert (7 ops).
// ---------------------------------------------------------------------------
__device__ __forceinline__ void ins4(float d, float& t0, float& t1, float& t2, float& t3) {
    float n0 = fminf(t0, d);  t0 = fmaxf(t0, d);
    float n1 = fminf(t1, n0); t1 = fmaxf(t1, n0);
    float n2 = fminf(t2, n1); t2 = fmaxf(t2, n1);
    t3 = fmaxf(t3, n2);
}

__device__ double digamma_d(double x) {
    // exact enough for integer args >= 1; threshold is 0.155 so this is overkill
    double r = 0.0;
    while (x < 6.0) { r -= 1.0 / x; x += 1.0; }
    double f = 1.0 / (x * x);
    double t = f * (1.0/12.0 - f * (1.0/120.0 - f * (1.0/252.0 - f * (1.0/240.0 - f * (1.0/132.0)))));
    return r + log(x) - 0.5 / x - t;
}

// ---------------------------------------------------------------------------
// K1: per-query partial top-4 of joint Chebyshev distance over a point split.
// grid = (NPTS/TPB, S); block handles 256 queries x pps points.
// Point loads are wave-uniform -> scalar (s_load) path expected.
// ---------------------------------------------------------------------------
__global__ __launch_bounds__(TPB) void knn_part_kernel(
    const float* __restrict__ x, const float* __restrict__ y,
    float4* __restrict__ part, int pps)
{
    const int q = blockIdx.x * TPB + threadIdx.x;
    float qv[32];
    {
        const float4* qx4 = reinterpret_cast<const float4*>(x) + (size_t)q * 4;
        const float4* qy4 = reinterpret_cast<const float4*>(y) + (size_t)q * 4;
        #pragma unroll
        for (int i = 0; i < 4; ++i) {
            float4 v = qx4[i];
            qv[4*i+0] = v.x; qv[4*i+1] = v.y; qv[4*i+2] = v.z; qv[4*i+3] = v.w;
        }
        #pragma unroll
        for (int i = 0; i < 4; ++i) {
            float4 v = qy4[i];
            qv[16+4*i+0] = v.x; qv[16+4*i+1] = v.y; qv[16+4*i+2] = v.z; qv[16+4*i+3] = v.w;
        }
    }

    float t0 = -1.0f, t1 = -1.0f, t2 = -1.0f, t3 = -1.0f; // distances >= 0

    const int j0 = blockIdx.y * pps;
    for (int j = j0; j < j0 + pps; ++j) {
        float p[32];
        {
            const float4* px4 = reinterpret_cast<const float4*>(x) + (size_t)j * 4;
            const float4* py4 = reinterpret_cast<const float4*>(y) + (size_t)j * 4;
            #pragma unroll
            for (int i = 0; i < 4; ++i) {
                float4 v = px4[i];
                p[4*i+0] = v.x; p[4*i+1] = v.y; p[4*i+2] = v.z; p[4*i+3] = v.w;
            }
            #pragma unroll
            for (int i = 0; i < 4; ++i) {
                float4 v = py4[i];
                p[16+4*i+0] = v.x; p[16+4*i+1] = v.y; p[16+4*i+2] = v.z; p[16+4*i+3] = v.w;
            }
        }
        float a[32];
        #pragma unroll
        for (int k = 0; k < 32; ++k) a[k] = fabsf(qv[k] - p[k]);
        #pragma unroll
        for (int s = 16; s > 0; s >>= 1) {
            #pragma unroll
            for (int k = 0; k < 32; ++k) { // only k<s active; guard below
                if (k < s) a[k] = fmaxf(a[k], a[k + s]);
            }
        }
        ins4(a[0], t0, t1, t2, t3);
    }
    part[(size_t)blockIdx.y * NPTS + q] = make_float4(t0, t1, t2, t3);
}

// ---------------------------------------------------------------------------
// K2: merge S partial top-4 lists per query -> radius r[q] = 4th largest - eps
// ---------------------------------------------------------------------------
__global__ __launch_bounds__(TPB) void knn_merge_kernel(
    const float4* __restrict__ part, float* __restrict__ r, int S)
{
    const int q = blockIdx.x * TPB + threadIdx.x;
    float t0 = -1.0f, t1 = -1.0f, t2 = -1.0f, t3 = -1.0f;
    for (int s = 0; s < S; ++s) {
        float4 v = part[(size_t)s * NPTS + q];
        ins4(v.x, t0, t1, t2, t3);
        ins4(v.y, t0, t1, t2, t3);
        ins4(v.z, t0, t1, t2, t3);
        ins4(v.w, t0, t1, t2, t3);
    }
    r[q] = t3 - 1e-15f; // exact fidelity to reference (no-op at f32 ulp)
}

// ---------------------------------------------------------------------------
// K3: partial inclusive range counts in X and Y marginals.
// ---------------------------------------------------------------------------
__global__ __launch_bounds__(TPB) void count_part_kernel(
    const float* __restrict__ x, const float* __restrict__ y,
    const float* __restrict__ r,
    int* __restrict__ cx, int* __restrict__ cy, int pps)
{
    const int q = blockIdx.x * TPB + threadIdx.x;
    float qx[16], qy[16];
    {
        const float4* qx4 = reinterpret_cast<const float4*>(x) + (size_t)q * 4;
        const float4* qy4 = reinterpret_cast<const float4*>(y) + (size_t)q * 4;
        #pragma unroll
        for (int i = 0; i < 4; ++i) {
            float4 v = qx4[i];
            qx[4*i+0] = v.x; qx[4*i+1] = v.y; qx[4*i+2] = v.z; qx[4*i+3] = v.w;
            float4 w = qy4[i];
            qy[4*i+0] = w.x; qy[4*i+1] = w.y; qy[4*i+2] = w.z; qy[4*i+3] = w.w;
        }
    }
    const float rq = r[q];
    int nx = 0, ny = 0;

    const int j0 = blockIdx.y * pps;
    for (int j = j0; j < j0 + pps; ++j) {
        float px[16], py[16];
        {
            const float4* px4 = reinterpret_cast<const float4*>(x) + (size_t)j * 4;
            const float4* py4 = reinterpret_cast<const float4*>(y) + (size_t)j * 4;
            #pragma unroll
            for (int i = 0; i < 4; ++i) {
                float4 v = px4[i];
                px[4*i+0] = v.x; px[4*i+1] = v.y; px[4*i+2] = v.z; px[4*i+3] = v.w;
                float4 w = py4[i];
                py[4*i+0] = w.x; py[4*i+1] = w.y; py[4*i+2] = w.z; py[4*i+3] = w.w;
            }
        }
        float ax[16], ay[16];
        #pragma unroll
        for (int k = 0; k < 16; ++k) {
            ax[k] = fabsf(qx[k] - px[k]);
            ay[k] = fabsf(qy[k] - py[k]);
        }
        #pragma unroll
        for (int s = 8; s > 0; s >>= 1) {
            #pragma unroll
            for (int k = 0; k < 8; ++k) {
                if (k < s) {
                    ax[k] = fmaxf(ax[k], ax[k + s]);
                    ay[k] = fmaxf(ay[k], ay[k + s]);
                }
            }
        }
        nx += (ax[0] <= rq) ? 1 : 0;
        ny += (ay[0] <= rq) ? 1 : 0;
    }
    cx[(size_t)blockIdx.y * NPTS + q] = nx;
    cy[(size_t)blockIdx.y * NPTS + q] = ny;
}

// ---------------------------------------------------------------------------
// K4: merge partial counts, compute digamma(nx)+digamma(ny) per query (f64).
// ---------------------------------------------------------------------------
__global__ __launch_bounds__(TPB) void count_merge_kernel(
    const int* __restrict__ cx, const int* __restrict__ cy,
    double* __restrict__ dig, int S)
{
    const int q = blockIdx.x * TPB + threadIdx.x;
    int nx = 0, ny = 0;
    for (int s = 0; s < S; ++s) {
        nx += cx[(size_t)s * NPTS + q];
        ny += cy[(size_t)s * NPTS + q];
    }
    dig[q] = digamma_d((double)nx) + digamma_d((double)ny);
}

// ---------------------------------------------------------------------------
// K5: final reduction; ans = psi(N) + psi(k) - mean(psi(nx)+psi(ny))
// (log terms of the reference cancel exactly in the x+y-xy combination)
// ---------------------------------------------------------------------------
__global__ __launch_bounds__(TPB) void final_kernel(
    const double* __restrict__ dig, float* __restrict__ out)
{
    __shared__ double sm[TPB];
    double s = 0.0;
    for (int i = threadIdx.x; i < NPTS; i += TPB) s += dig[i];
    sm[threadIdx.x] = s;
    __syncthreads();
    for (int w = TPB / 2; w > 0; w >>= 1) {
        if (threadIdx.x < w) sm[threadIdx.x] += sm[threadIdx.x + w];
        __syncthreads();
    }
    if (threadIdx.x == 0) {
        double ans = digamma_d((double)NPTS) + digamma_d(4.0) - sm[0] / (double)NPTS;
        out[0] = (float)ans;
    }
}

// ---------------------------------------------------------------------------
extern "C" void kernel_launch(void* const* d_in, const int* in_sizes, int n_in,
                              void* d_out, int out_size, void* d_ws, size_t ws_size,
                              hipStream_t stream)
{
    (void)in_sizes; (void)n_in; (void)out_size;
    const float* x = (const float*)d_in[0];
    const float* y = (const float*)d_in[1];
    float* out = (float*)d_out;

    // workspace layout (8-byte aligned first):
    //   dig:  NPTS doubles              (64 KB)
    //   r:    NPTS floats               (32 KB)
    //   part: S*NPTS float4             (S * 128 KB)
    //   cx:   S*NPTS int                (S * 32 KB)
    //   cy:   S*NPTS int                (S * 32 KB)
    char* ws = (char*)d_ws;
    double* dig = (double*)ws;
    float*  r   = (float*)(ws + (size_t)NPTS * 8);
    char*   p0  = ws + (size_t)NPTS * 8 + (size_t)NPTS * 4;

    int S = 64;
    while (S > 1) {
        size_t need = (size_t)NPTS * 12 + (size_t)S * NPTS * 16 + (size_t)S * NPTS * 8;
        if (need <= ws_size) break;
        S >>= 1;
    }
    float4* part = (float4*)p0;
    int* cx = (int*)(p0 + (size_t)S * NPTS * 16);
    int* cy = cx + (size_t)S * NPTS;
    const int pps = NPTS / S;

    dim3 gridP(NPTS / TPB, S);
    knn_part_kernel<<<gridP, TPB, 0, stream>>>(x, y, part, pps);
    knn_merge_kernel<<<NPTS / TPB, TPB, 0, stream>>>(part, r, S);
    count_part_kernel<<<gridP, TPB, 0, stream>>>(x, y, r, cx, cy, pps);
    count_merge_kernel<<<NPTS / TPB, TPB, 0, stream>>>(cx, cy, dig, S);
    final_kernel<<<1, TPB, 0, stream>>>(dig, out);
}

// Round 2
// 300.476 us; speedup vs baseline: 1.0017x; 1.0017x over previous
//
#include <hip/hip_runtime.h>
#include <math.h>

#define NPTS 8192
#define TPB  256
#define TILE 128   // points staged per LDS tile (TILE*32 floats = 16 KB)

// ---------------------------------------------------------------------------
// Branchless sorted-descending top-4 insert (7 ops).
// ---------------------------------------------------------------------------
__device__ __forceinline__ void ins4(float d, float& t0, float& t1, float& t2, float& t3) {
    float n0 = fminf(t0, d);  t0 = fmaxf(t0, d);
    float n1 = fminf(t1, n0); t1 = fmaxf(t1, n0);
    float n2 = fminf(t2, n1); t2 = fmaxf(t2, n1);
    t3 = fmaxf(t3, n2);
}

__device__ double digamma_d(double x) {
    double r = 0.0;
    while (x < 6.0) { r -= 1.0 / x; x += 1.0; }
    double f = 1.0 / (x * x);
    double t = f * (1.0/12.0 - f * (1.0/120.0 - f * (1.0/252.0 - f * (1.0/240.0 - f * (1.0/132.0)))));
    return r + log(x) - 0.5 / x - t;
}

// ---------------------------------------------------------------------------
// Cooperative stage of TILE points (x:16 + y:16 floats each) into LDS.
// Layout: pts4[pt*8 + c], c<4 = x float4s, c>=4 = y float4s.
// ---------------------------------------------------------------------------
__device__ __forceinline__ void stage_tile(
    float4* pts4, const float* __restrict__ x, const float* __restrict__ y, int jt)
{
    #pragma unroll
    for (int i = 0; i < (TILE * 8) / TPB; ++i) {
        int li = i * TPB + threadIdx.x;         // 0 .. TILE*8-1
        int pt = li >> 3, c = li & 7;
        const float4* src = (c < 4)
            ? reinterpret_cast<const float4*>(x) + (size_t)(jt + pt) * 4 + c
            : reinterpret_cast<const float4*>(y) + (size_t)(jt + pt) * 4 + (c - 4);
        pts4[li] = *src;
    }
}

// ---------------------------------------------------------------------------
// K1: per-query partial top-4 of joint Chebyshev distance over a point split.
// grid = (NPTS/TPB, S). Points staged in LDS; inner reads are wave-uniform
// ds_read_b128 broadcasts (conflict-free, off the VALU critical path).
// ---------------------------------------------------------------------------
__global__ __launch_bounds__(TPB) void knn_part_kernel(
    const float* __restrict__ x, const float* __restrict__ y,
    float4* __restrict__ part, int pps)
{
    __shared__ float4 pts4[TILE * 8];
    const int q = blockIdx.x * TPB + threadIdx.x;
    float qv[32];
    {
        const float4* qx4 = reinterpret_cast<const float4*>(x) + (size_t)q * 4;
        const float4* qy4 = reinterpret_cast<const float4*>(y) + (size_t)q * 4;
        #pragma unroll
        for (int i = 0; i < 4; ++i) {
            float4 v = qx4[i];
            qv[4*i+0] = v.x; qv[4*i+1] = v.y; qv[4*i+2] = v.z; qv[4*i+3] = v.w;
            float4 w = qy4[i];
            qv[16+4*i+0] = w.x; qv[16+4*i+1] = w.y; qv[16+4*i+2] = w.z; qv[16+4*i+3] = w.w;
        }
    }

    float t0 = -1.0f, t1 = -1.0f, t2 = -1.0f, t3 = -1.0f;

    const int j0 = blockIdx.y * pps;
    for (int jt = j0; jt < j0 + pps; jt += TILE) {
        stage_tile(pts4, x, y, jt);
        __syncthreads();
        #pragma unroll 2
        for (int jj = 0; jj < TILE; ++jj) {
            float a[32];
            #pragma unroll
            for (int i = 0; i < 8; ++i) {
                float4 v = pts4[jj * 8 + i];    // wave-uniform -> broadcast
                a[4*i+0] = v.x; a[4*i+1] = v.y; a[4*i+2] = v.z; a[4*i+3] = v.w;
            }
            #pragma unroll
            for (int k = 0; k < 32; ++k) a[k] = fabsf(qv[k] - a[k]);
            #pragma unroll
            for (int s = 16; s > 0; s >>= 1) {
                #pragma unroll
                for (int k = 0; k < 16; ++k)
                    if (k < s) a[k] = fmaxf(a[k], a[k + s]);
            }
            ins4(a[0], t0, t1, t2, t3);
        }
        __syncthreads();
    }
    part[(size_t)blockIdx.y * NPTS + q] = make_float4(t0, t1, t2, t3);
}

// ---------------------------------------------------------------------------
// K2: merge S partial top-4 lists per query -> radius r[q] = 4th largest - eps
// ---------------------------------------------------------------------------
__global__ __launch_bounds__(TPB) void knn_merge_kernel(
    const float4* __restrict__ part, float* __restrict__ r, int S)
{
    const int q = blockIdx.x * TPB + threadIdx.x;
    float t0 = -1.0f, t1 = -1.0f, t2 = -1.0f, t3 = -1.0f;
    for (int s = 0; s < S; ++s) {
        float4 v = part[(size_t)s * NPTS + q];
        ins4(v.x, t0, t1, t2, t3);
        ins4(v.y, t0, t1, t2, t3);
        ins4(v.z, t0, t1, t2, t3);
        ins4(v.w, t0, t1, t2, t3);
    }
    r[q] = t3 - 1e-15f;
}

// ---------------------------------------------------------------------------
// K3: partial inclusive range counts in X and Y marginals (LDS-staged).
// ---------------------------------------------------------------------------
__global__ __launch_bounds__(TPB) void count_part_kernel(
    const float* __restrict__ x, const float* __restrict__ y,
    const float* __restrict__ r,
    int* __restrict__ cx, int* __restrict__ cy, int pps)
{
    __shared__ float4 pts4[TILE * 8];
    const int q = blockIdx.x * TPB + threadIdx.x;
    float qv[32];
    {
        const float4* qx4 = reinterpret_cast<const float4*>(x) + (size_t)q * 4;
        const float4* qy4 = reinterpret_cast<const float4*>(y) + (size_t)q * 4;
        #pragma unroll
        for (int i = 0; i < 4; ++i) {
            float4 v = qx4[i];
            qv[4*i+0] = v.x; qv[4*i+1] = v.y; qv[4*i+2] = v.z; qv[4*i+3] = v.w;
            float4 w = qy4[i];
            qv[16+4*i+0] = w.x; qv[16+4*i+1] = w.y; qv[16+4*i+2] = w.z; qv[16+4*i+3] = w.w;
        }
    }
    const float rq = r[q];
    int nx = 0, ny = 0;

    const int j0 = blockIdx.y * pps;
    for (int jt = j0; jt < j0 + pps; jt += TILE) {
        stage_tile(pts4, x, y, jt);
        __syncthreads();
        #pragma unroll 2
        for (int jj = 0; jj < TILE; ++jj) {
            float a[32];
            #pragma unroll
            for (int i = 0; i < 8; ++i) {
                float4 v = pts4[jj * 8 + i];    // wave-uniform -> broadcast
                a[4*i+0] = v.x; a[4*i+1] = v.y; a[4*i+2] = v.z; a[4*i+3] = v.w;
            }
            #pragma unroll
            for (int k = 0; k < 32; ++k) a[k] = fabsf(qv[k] - a[k]);
            // separate 16-dim max trees for the X and Y marginals
            #pragma unroll
            for (int s = 8; s > 0; s >>= 1) {
                #pragma unroll
                for (int k = 0; k < 8; ++k)
                    if (k < s) {
                        a[k]      = fmaxf(a[k],      a[k + s]);
                        a[16 + k] = fmaxf(a[16 + k], a[16 + k + s]);
                    }
            }
            nx += (a[0]  <= rq) ? 1 : 0;
            ny += (a[16] <= rq) ? 1 : 0;
        }
        __syncthreads();
    }
    cx[(size_t)blockIdx.y * NPTS + q] = nx;
    cy[(size_t)blockIdx.y * NPTS + q] = ny;
}

// ---------------------------------------------------------------------------
// K4: merge partial counts -> digamma(nx)+digamma(ny) per query (f64).
// ---------------------------------------------------------------------------
__global__ __launch_bounds__(TPB) void count_merge_kernel(
    const int* __restrict__ cx, const int* __restrict__ cy,
    double* __restrict__ dig, int S)
{
    const int q = blockIdx.x * TPB + threadIdx.x;
    int nx = 0, ny = 0;
    for (int s = 0; s < S; ++s) {
        nx += cx[(size_t)s * NPTS + q];
        ny += cy[(size_t)s * NPTS + q];
    }
    dig[q] = digamma_d((double)nx) + digamma_d((double)ny);
}

// ---------------------------------------------------------------------------
// K5: final reduction; ans = psi(N) + psi(k) - mean(psi(nx)+psi(ny))
// (log/log2 terms of the reference cancel exactly in ans_x+ans_y-ans_xy)
// ---------------------------------------------------------------------------
__global__ __launch_bounds__(TPB) void final_kernel(
    const double* __restrict__ dig, float* __restrict__ out)
{
    __shared__ double sm[TPB];
    double s = 0.0;
    for (int i = threadIdx.x; i < NPTS; i += TPB) s += dig[i];
    sm[threadIdx.x] = s;
    __syncthreads();
    for (int w = TPB / 2; w > 0; w >>= 1) {
        if (threadIdx.x < w) sm[threadIdx.x] += sm[threadIdx.x + w];
        __syncthreads();
    }
    if (threadIdx.x == 0) {
        double ans = digamma_d((double)NPTS) + digamma_d(4.0) - sm[0] / (double)NPTS;
        out[0] = (float)ans;
    }
}

// ---------------------------------------------------------------------------
extern "C" void kernel_launch(void* const* d_in, const int* in_sizes, int n_in,
                              void* d_out, int out_size, void* d_ws, size_t ws_size,
                              hipStream_t stream)
{
    (void)in_sizes; (void)n_in; (void)out_size;
    const float* x = (const float*)d_in[0];
    const float* y = (const float*)d_in[1];
    float* out = (float*)d_out;

    char* ws = (char*)d_ws;
    double* dig = (double*)ws;
    float*  r   = (float*)(ws + (size_t)NPTS * 8);
    char*   p0  = ws + (size_t)NPTS * 8 + (size_t)NPTS * 4;

    int S = 64;
    while (S > 1) {
        size_t need = (size_t)NPTS * 12 + (size_t)S * NPTS * 16 + (size_t)S * NPTS * 8;
        if (need <= ws_size) break;
        S >>= 1;
    }
    float4* part = (float4*)p0;
    int* cx = (int*)(p0 + (size_t)S * NPTS * 16);
    int* cy = cx + (size_t)S * NPTS;
    const int pps = NPTS / S;   // S<=64 -> pps>=128, multiple of TILE

    dim3 gridP(NPTS / TPB, S);
    knn_part_kernel<<<gridP, TPB, 0, stream>>>(x, y, part, pps);
    knn_merge_kernel<<<NPTS / TPB, TPB, 0, stream>>>(part, r, S);
    count_part_kernel<<<gridP, TPB, 0, stream>>>(x, y, r, cx, cy, pps);
    count_merge_kernel<<<NPTS / TPB, TPB, 0, stream>>>(cx, cy, dig, S);
    final_kernel<<<1, TPB, 0, stream>>>(dig, out);
}